// Round 4
// baseline (226.510 us; speedup 1.0000x reference)
//
#include <hip/hip_runtime.h>
#include <hip/hip_bf16.h>
#include <math.h>

#define BATCH 4096
#define SEQ 200
#define EMB 512
#define VOCAB 100000

typedef __attribute__((ext_vector_type(8))) short bf16x8;
typedef __attribute__((ext_vector_type(4))) float f32x4;

// ---------------------------------------------------------------------------
// bf16 helpers (RNE float->bf16; cheap bf16->float via bit ops)
// ---------------------------------------------------------------------------
__device__ inline unsigned int f2bf(float f) {
    unsigned int u = __float_as_uint(f);
    return (u + 0x7FFFu + ((u >> 16) & 1u)) >> 16;
}
__device__ inline unsigned int pack2(float lo, float hi) {
    return f2bf(lo) | (f2bf(hi) << 16);
}
__device__ inline float bflo(unsigned int u) { return __uint_as_float(u << 16); }
__device__ inline float bfhi(unsigned int u) { return __uint_as_float(u & 0xFFFF0000u); }

// ---------------------------------------------------------------------------
// Kernel 0a: convert E (fp32 [VOCAB x EMB]) -> bf16 table.
// ---------------------------------------------------------------------------
__global__ __launch_bounds__(256) void convert_E_bf16(
    const float* __restrict__ E, unsigned int* __restrict__ Eb4, int n8)
{
    const int stride = gridDim.x * 256;
    for (int i = blockIdx.x * 256 + threadIdx.x; i < n8; i += stride) {
        const float4* p = reinterpret_cast<const float4*>(E) + (size_t)i * 2;
        float4 a = p[0], b = p[1];
        uint4 o;
        o.x = pack2(a.x, a.y);
        o.y = pack2(a.z, a.w);
        o.z = pack2(b.x, b.y);
        o.w = pack2(b.z, b.w);
        reinterpret_cast<uint4*>(Eb4)[i] = o;
    }
}

// ---------------------------------------------------------------------------
// Kernel 0b: W [K x N] fp32 -> WT [N x K] bf16 (transpose via LDS 32x32 tile).
// ---------------------------------------------------------------------------
__global__ __launch_bounds__(256) void convert_WT_bf16(
    const float* __restrict__ W, short* __restrict__ WT, int K, int N)
{
    __shared__ float lds[32][33];
    const int tx = threadIdx.x & 31;
    const int ty = threadIdx.x >> 5;
    const int n0 = blockIdx.x * 32;
    const int k0 = blockIdx.y * 32;
#pragma unroll
    for (int i = 0; i < 4; ++i)
        lds[ty + 8 * i][tx] = W[(size_t)(k0 + ty + 8 * i) * N + n0 + tx];
    __syncthreads();
#pragma unroll
    for (int i = 0; i < 4; ++i)
        WT[(size_t)(n0 + ty + 8 * i) * K + k0 + tx] =
            (short)f2bf(lds[tx][ty + 8 * i]);
}

// ---------------------------------------------------------------------------
// Kernel 1a: embedding bag from bf16 table -> bf16 sent.
// One block per batch row, 4 waves; each wave reads whole 1KB rows
// (64 lanes x 16B). 4-deep explicit load batching for MLP: issue 4
// independent row loads, then accumulate all 4. fp32 accumulate; LDS reduce.
// ---------------------------------------------------------------------------
__global__ __launch_bounds__(256) void embed_mean_bf16(
    const int* __restrict__ idx, const unsigned int* __restrict__ Eb,
    unsigned int* __restrict__ sentB)
{
    __shared__ int sIdx[SEQ];
    __shared__ float red[3 * 512];
    const int b = blockIdx.x;
    const int t = threadIdx.x;
    if (t < SEQ) sIdx[t] = idx[b * SEQ + t];
    __syncthreads();

    const int g = t >> 6;      // wave id 0..3
    const int lane = t & 63;   // 16B chunk within row
    float acc[8] = {};

#define ROWPTR(s) (reinterpret_cast<const uint4*>(Eb + (size_t)sIdx[(s)] * (EMB / 2)) + lane)
#define ACCUM(v)                                            \
    do {                                                    \
        acc[0] += bflo((v).x); acc[1] += bfhi((v).x);       \
        acc[2] += bflo((v).y); acc[3] += bfhi((v).y);       \
        acc[4] += bflo((v).z); acc[5] += bfhi((v).z);       \
        acc[6] += bflo((v).w); acc[7] += bfhi((v).w);       \
    } while (0)

    // 50 rows per wave: 12 batches of 4 + 1 batch of 2.
    int s = g;
#pragma unroll 1
    for (int it = 0; it < 12; ++it) {
        uint4 v0 = *ROWPTR(s);
        uint4 v1 = *ROWPTR(s + 4);
        uint4 v2 = *ROWPTR(s + 8);
        uint4 v3 = *ROWPTR(s + 12);
        ACCUM(v0);
        ACCUM(v1);
        ACCUM(v2);
        ACCUM(v3);
        s += 16;
    }
    {
        uint4 v0 = *ROWPTR(s);
        uint4 v1 = *ROWPTR(s + 4);
        ACCUM(v0);
        ACCUM(v1);
    }
#undef ROWPTR
#undef ACCUM

    if (g) {
        float4* r = reinterpret_cast<float4*>(&red[(g - 1) * 512 + lane * 8]);
        r[0] = make_float4(acc[0], acc[1], acc[2], acc[3]);
        r[1] = make_float4(acc[4], acc[5], acc[6], acc[7]);
    }
    __syncthreads();
    if (g == 0) {
        const float sc = 1.0f / (float)SEQ;
        float o[8];
#pragma unroll
        for (int j = 0; j < 8; ++j)
            o[j] = (acc[j] + red[0 * 512 + lane * 8 + j] +
                    red[1 * 512 + lane * 8 + j] + red[2 * 512 + lane * 8 + j]) * sc;
        uint4 pk;
        pk.x = pack2(o[0], o[1]);
        pk.y = pack2(o[2], o[3]);
        pk.z = pack2(o[4], o[5]);
        pk.w = pack2(o[6], o[7]);
        reinterpret_cast<uint4*>(sentB + (size_t)b * 256)[lane] = pk;
    }
}

// ---------------------------------------------------------------------------
// Kernel 1b (fallback fp32 gather)
// ---------------------------------------------------------------------------
__global__ __launch_bounds__(256) void embed_mean_kernel(
    const int* __restrict__ idx, const float* __restrict__ E,
    float* __restrict__ sent)
{
    __shared__ int sIdx[SEQ];
    __shared__ float4 red[128];
    const int b = blockIdx.x;
    const int t = threadIdx.x;
    if (t < SEQ) sIdx[t] = idx[b * SEQ + t];
    __syncthreads();

    const int half = t >> 7;
    const int lane = t & 127;
    float4 acc = make_float4(0.f, 0.f, 0.f, 0.f);
    for (int s = half; s < SEQ; s += 2) {
        const float4* row =
            reinterpret_cast<const float4*>(E + (size_t)sIdx[s] * EMB);
        float4 v = row[lane];
        acc.x += v.x; acc.y += v.y; acc.z += v.z; acc.w += v.w;
    }
    if (half == 1) red[lane] = acc;
    __syncthreads();
    if (half == 0) {
        float4 o = red[lane];
        const float sc = 1.0f / (float)SEQ;
        float4 r;
        r.x = (acc.x + o.x) * sc;
        r.y = (acc.y + o.y) * sc;
        r.z = (acc.z + o.z) * sc;
        r.w = (acc.w + o.w) * sc;
        reinterpret_cast<float4*>(sent + (size_t)b * EMB)[lane] = r;
    }
}

// ---------------------------------------------------------------------------
// Kernel 2a: bf16 MFMA GEMM, C = relu(A @ B + bias).
// A: bf16 [M][K] row-major. BT: bf16 [N][K]. BM=128, BN=64, BK=32;
// 256 threads = 4 waves (2x2); wave computes 64x32 output.
// ---------------------------------------------------------------------------
template <int N, int K, bool OUT_BF16>
__global__ __launch_bounds__(256) void gemm_mfma_bias_relu(
    const short* __restrict__ A, const short* __restrict__ BT,
    const float* __restrict__ bias, void* __restrict__ C)
{
    constexpr int BM = 128, BN = 64, BK = 32;
    __shared__ float4 As[512];
    __shared__ float4 Bs[256];

    const int t = threadIdx.x;
    const int l = t & 63;
    const int w = t >> 6;
    const int wr = w >> 1;
    const int wc = w & 1;
    const int m0 = blockIdx.x * BM;
    const int n0 = blockIdx.y * BN;

    const int srow = (t >> 6) * 16 + (t & 15);
    const int skg = (t >> 4) & 3;

    f32x4 acc[4][2] = {};

    for (int kt = 0; kt < K; kt += BK) {
        const float4 a0 = *reinterpret_cast<const float4*>(
            A + (size_t)(m0 + srow) * K + kt + skg * 8);
        const float4 a1 = *reinterpret_cast<const float4*>(
            A + (size_t)(m0 + srow + 64) * K + kt + skg * 8);
        const float4 b0 = *reinterpret_cast<const float4*>(
            BT + (size_t)(n0 + srow) * K + kt + skg * 8);
        __syncthreads();
        As[t] = a0;
        As[t + 256] = a1;
        Bs[t] = b0;
        __syncthreads();

        bf16x8 afr[4], bfr[2];
#pragma unroll
        for (int f = 0; f < 4; ++f)
            afr[f] = *reinterpret_cast<const bf16x8*>(
                &As[(wr * 4 + f) * 64 + (l >> 4) * 16 + (l & 15)]);
#pragma unroll
        for (int g = 0; g < 2; ++g)
            bfr[g] = *reinterpret_cast<const bf16x8*>(
                &Bs[(wc * 2 + g) * 64 + (l >> 4) * 16 + (l & 15)]);
#pragma unroll
        for (int f = 0; f < 4; ++f)
#pragma unroll
            for (int g = 0; g < 2; ++g)
                acc[f][g] = __builtin_amdgcn_mfma_f32_16x16x32_bf16(
                    afr[f], bfr[g], acc[f][g], 0, 0, 0);
    }

#pragma unroll
    for (int g = 0; g < 2; ++g) {
        const int col = n0 + wc * 32 + g * 16 + (l & 15);
        const float bv = bias[col];
#pragma unroll
        for (int f = 0; f < 4; ++f) {
#pragma unroll
            for (int r = 0; r < 4; ++r) {
                const int row = m0 + wr * 64 + f * 16 + (l >> 4) * 4 + r;
                const float v = fmaxf(acc[f][g][r] + bv, 0.f);
                if (OUT_BF16)
                    ((short*)C)[(size_t)row * N + col] = (short)f2bf(v);
                else
                    ((float*)C)[(size_t)row * N + col] = v;
            }
        }
    }
}

// ---------------------------------------------------------------------------
// Kernel 2b: fp32 tiled GEMM, C = relu(A @ W + bias). (L3/L4 + fallback)
// ---------------------------------------------------------------------------
template <int N, int K>
__global__ __launch_bounds__(256) void gemm_bias_relu(
    const float* __restrict__ A, const float* __restrict__ W,
    const float* __restrict__ bias, float* __restrict__ C)
{
    constexpr int BM = 64, BN = 64, BK = 16, LDT = 68;
    __shared__ float As[BK][LDT];
    __shared__ float Bs[BK][LDT];

    const int t = threadIdx.x;
    const int m0 = blockIdx.x * BM;
    const int n0 = blockIdx.y * BN;

    const int arow = t >> 2;
    const int acg  = (t & 3) * 4;
    const int brow = t >> 4;
    const int bcg  = (t & 15) * 4;

    const int tr = (t >> 4) * 4;
    const int tc = (t & 15) * 4;

    float acc[4][4] = {};

    for (int kt = 0; kt < K; kt += BK) {
        float4 av = *reinterpret_cast<const float4*>(
            &A[(size_t)(m0 + arow) * K + kt + acg]);
        float4 bv = *reinterpret_cast<const float4*>(
            &W[(size_t)(kt + brow) * N + n0 + bcg]);
        __syncthreads();
        As[acg + 0][arow] = av.x;
        As[acg + 1][arow] = av.y;
        As[acg + 2][arow] = av.z;
        As[acg + 3][arow] = av.w;
        *reinterpret_cast<float4*>(&Bs[brow][bcg]) = bv;
        __syncthreads();
#pragma unroll
        for (int kk = 0; kk < BK; ++kk) {
            float4 a4 = *reinterpret_cast<const float4*>(&As[kk][tr]);
            float4 b4 = *reinterpret_cast<const float4*>(&Bs[kk][tc]);
            float aa[4] = {a4.x, a4.y, a4.z, a4.w};
            float bb[4] = {b4.x, b4.y, b4.z, b4.w};
#pragma unroll
            for (int i = 0; i < 4; ++i)
#pragma unroll
                for (int j = 0; j < 4; ++j)
                    acc[i][j] = fmaf(aa[i], bb[j], acc[i][j]);
        }
    }

    float4 bias4 = *reinterpret_cast<const float4*>(&bias[n0 + tc]);
    float bb[4] = {bias4.x, bias4.y, bias4.z, bias4.w};
#pragma unroll
    for (int i = 0; i < 4; ++i) {
        float4 r;
        r.x = fmaxf(acc[i][0] + bb[0], 0.f);
        r.y = fmaxf(acc[i][1] + bb[1], 0.f);
        r.z = fmaxf(acc[i][2] + bb[2], 0.f);
        r.w = fmaxf(acc[i][3] + bb[3], 0.f);
        *reinterpret_cast<float4*>(&C[(size_t)(m0 + tr + i) * N + n0 + tc]) = r;
    }
}

// ---------------------------------------------------------------------------
// Kernel 3: final layer (K=64, N=3) + softmax. One thread per batch row.
// ---------------------------------------------------------------------------
__global__ __launch_bounds__(256) void final_softmax_kernel(
    const float* __restrict__ h4, const float* __restrict__ W5,
    const float* __restrict__ b5, float* __restrict__ out)
{
    __shared__ float w[64 * 3];
    __shared__ float bb[3];
    const int t = threadIdx.x;
    if (t < 192) w[t] = W5[t];
    if (t < 3) bb[t] = b5[t];
    __syncthreads();

    const int row = blockIdx.x * 256 + t;
    float a0 = bb[0], a1 = bb[1], a2 = bb[2];
    const float* hr = h4 + (size_t)row * 64;
#pragma unroll
    for (int k = 0; k < 64; ++k) {
        float h = hr[k];
        a0 = fmaf(h, w[k * 3 + 0], a0);
        a1 = fmaf(h, w[k * 3 + 1], a1);
        a2 = fmaf(h, w[k * 3 + 2], a2);
    }
    float m  = fmaxf(a0, fmaxf(a1, a2));
    float e0 = expf(a0 - m), e1 = expf(a1 - m), e2 = expf(a2 - m);
    float inv = 1.0f / (e0 + e1 + e2);
    out[row * 3 + 0] = e0 * inv;
    out[row * 3 + 1] = e1 * inv;
    out[row * 3 + 2] = e2 * inv;
}

// ---------------------------------------------------------------------------
// Workspace layout (bf16 path), bytes:
//   Eb    @ 0           : 102,400,000  (bf16 E)
//   W1T   @ 102,400,000 :     524,288
//   W2T   @ 102,924,288 :     262,144
//   sentB @ 103,186,432 :   4,194,304
//   h1B   @ 107,380,736 :   4,194,304
//   h2    @ 111,575,040 :   4,194,304
//   h3    @ 115,769,344 :   2,097,152
//   h4    @ 117,866,496 :   1,048,576   total 118,915,072
// ---------------------------------------------------------------------------
extern "C" void kernel_launch(void* const* d_in, const int* in_sizes, int n_in,
                              void* d_out, int out_size, void* d_ws,
                              size_t ws_size, hipStream_t stream)
{
    const int*   inputs = (const int*)d_in[0];
    const float* E  = (const float*)d_in[1];
    const float* W1 = (const float*)d_in[2];
    const float* b1 = (const float*)d_in[3];
    const float* W2 = (const float*)d_in[4];
    const float* b2 = (const float*)d_in[5];
    const float* W3 = (const float*)d_in[6];
    const float* b3 = (const float*)d_in[7];
    const float* W4 = (const float*)d_in[8];
    const float* b4 = (const float*)d_in[9];
    const float* W5 = (const float*)d_in[10];
    const float* b5 = (const float*)d_in[11];
    float* out = (float*)d_out;

    const size_t ebBytes = (size_t)VOCAB * EMB * 2;
    const size_t needed = ebBytes + 524288 + 262144 + 3 * 4194304 + 2097152 + 1048576;

    if (ws_size >= needed) {
        char* p = (char*)d_ws;
        unsigned int* Eb    = (unsigned int*)p;
        short*        W1T   = (short*)(p + ebBytes);
        short*        W2T   = (short*)(p + ebBytes + 524288);
        unsigned int* sentB = (unsigned int*)(p + ebBytes + 786432);
        short*        h1B   = (short*)(p + ebBytes + 786432 + 4194304);
        float*        h2    = (float*)(p + ebBytes + 786432 + 2 * 4194304);
        float*        h3    = (float*)(p + ebBytes + 786432 + 3 * 4194304);
        float*        h4    = (float*)(p + ebBytes + 786432 + 3 * 4194304 + 2097152);

        convert_E_bf16<<<2048, 256, 0, stream>>>(E, Eb, VOCAB * EMB / 8);
        convert_WT_bf16<<<dim3(512 / 32, 512 / 32), 256, 0, stream>>>(W1, W1T, 512, 512);
        convert_WT_bf16<<<dim3(256 / 32, 512 / 32), 256, 0, stream>>>(W2, W2T, 512, 256);
        embed_mean_bf16<<<BATCH, 256, 0, stream>>>(inputs, Eb, sentB);

        gemm_mfma_bias_relu<512, 512, true>
            <<<dim3(BATCH / 128, 512 / 64), 256, 0, stream>>>(
                (const short*)sentB, W1T, b1, (void*)h1B);
        gemm_mfma_bias_relu<256, 512, false>
            <<<dim3(BATCH / 128, 256 / 64), 256, 0, stream>>>(
                h1B, W2T, b2, (void*)h2);
        gemm_bias_relu<128, 256><<<dim3(BATCH / 64, 2), 256, 0, stream>>>(
            h2, W3, b3, h3);
        gemm_bias_relu<64, 128><<<dim3(BATCH / 64, 1), 256, 0, stream>>>(
            h3, W4, b4, h4);
        final_softmax_kernel<<<BATCH / 256, 256, 0, stream>>>(h4, W5, b5, out);
    } else {
        float* act  = (float*)d_ws;
        float* sent = act;
        float* h1   = act + 2097152;
        float* h2   = act;
        float* h3   = act + 2097152;
        float* h4   = act;
        embed_mean_kernel<<<BATCH, 256, 0, stream>>>(inputs, E, sent);
        gemm_bias_relu<512, 512><<<dim3(BATCH / 64, 8), 256, 0, stream>>>(
            sent, W1, b1, h1);
        gemm_bias_relu<256, 512><<<dim3(BATCH / 64, 4), 256, 0, stream>>>(
            h1, W2, b2, h2);
        gemm_bias_relu<128, 256><<<dim3(BATCH / 64, 2), 256, 0, stream>>>(
            h2, W3, b3, h3);
        gemm_bias_relu<64, 128><<<dim3(BATCH / 64, 1), 256, 0, stream>>>(
            h3, W4, b4, h4);
        final_softmax_kernel<<<BATCH / 256, 256, 0, stream>>>(h4, W5, b5, out);
    }
}

// Round 5
// 170.223 us; speedup vs baseline: 1.3307x; 1.3307x over previous
//
#include <hip/hip_runtime.h>
#include <hip/hip_bf16.h>
#include <math.h>

#define BATCH 4096
#define SEQ 200
#define EMB 512
#define VOCAB 100000

typedef __attribute__((ext_vector_type(8))) short bf16x8;
typedef __attribute__((ext_vector_type(4))) float f32x4;
typedef __attribute__((ext_vector_type(4))) float f32x4v;
typedef __attribute__((ext_vector_type(2))) unsigned int u32x2;

// ---------------------------------------------------------------------------
// bf16 helpers
// ---------------------------------------------------------------------------
__device__ inline unsigned int f2bf(float f) {
    unsigned int u = __float_as_uint(f);
    return (u + 0x7FFFu + ((u >> 16) & 1u)) >> 16;
}
__device__ inline unsigned int pack2(float lo, float hi) {
    return f2bf(lo) | (f2bf(hi) << 16);
}
__device__ inline float bflo(unsigned int u) { return __uint_as_float(u << 16); }
__device__ inline float bfhi(unsigned int u) { return __uint_as_float(u & 0xFFFF0000u); }

// ---------------------------------------------------------------------------
// fp8 e4m3 (OCP) encode/decode. Primary path: gfx950 hardware cvt builtins.
// ---------------------------------------------------------------------------
#if __has_builtin(__builtin_amdgcn_cvt_pk_fp8_f32) && __has_builtin(__builtin_amdgcn_cvt_f32_fp8)
#define FP8_HW 1
#else
#define FP8_HW 0
// software RNE fallback (normals + subnormals + clamp at 448)
__device__ inline unsigned int fp8_enc_sw(float f) {
    unsigned int u = __float_as_uint(f);
    unsigned int s = u >> 31;
    u &= 0x7fffffffu;
    float a = __uint_as_float(u);
    if (a < 0.015625f) {  // subnormal: round a / 2^-9
        unsigned int m = (unsigned int)(int)rintf(a * 512.0f);
        return (s << 7) | m;  // m==8 carries into exp=1 correctly
    }
    if (a >= 448.0f) return (s << 7) | 0x7e;
    u += 0x7FFFFu + ((u >> 20) & 1u);  // RNE into bit 20
    unsigned int e = ((u >> 23) & 0xff) - 120u;
    unsigned int m = (u >> 20) & 7u;
    if (e > 15u || (e == 15u && m == 7u)) return (s << 7) | 0x7e;
    return (s << 7) | (e << 3) | m;
}
__device__ inline float fp8_dec_sw(unsigned int b) {
    unsigned int s = (b >> 7) & 1u, em = b & 0x7fu;
    float v;
    if (em >= 8u)
        v = __uint_as_float((((em >> 3) + 120u) << 23) | ((em & 7u) << 20));
    else
        v = (float)em * 0.001953125f;  // m * 2^-9
    return s ? -v : v;
}
#endif

__device__ inline unsigned int fp8_pack4(float a, float b, float c, float d) {
#if FP8_HW
    int w = __builtin_amdgcn_cvt_pk_fp8_f32(a, b, 0, false);
    w = __builtin_amdgcn_cvt_pk_fp8_f32(c, d, w, true);
    return (unsigned int)w;
#else
    return fp8_enc_sw(a) | (fp8_enc_sw(b) << 8) | (fp8_enc_sw(c) << 16) |
           (fp8_enc_sw(d) << 24);
#endif
}

// ---------------------------------------------------------------------------
// Kernel 0a: convert E (fp32 [VOCAB x EMB]) -> fp8 e4m3 table (51.2 MB).
// Non-temporal reads of E keep the fp8 table L3-resident for the gather.
// ---------------------------------------------------------------------------
__global__ __launch_bounds__(256) void convert_E_fp8(
    const float* __restrict__ E, u32x2* __restrict__ Eb, int n8)
{
    const int stride = gridDim.x * 256;
    for (int i = blockIdx.x * 256 + threadIdx.x; i < n8; i += stride) {
        const f32x4v* p = reinterpret_cast<const f32x4v*>(E) + (size_t)i * 2;
        f32x4v a = __builtin_nontemporal_load(p);
        f32x4v b = __builtin_nontemporal_load(p + 1);
        u32x2 o;
        o.x = fp8_pack4(a.x, a.y, a.z, a.w);
        o.y = fp8_pack4(b.x, b.y, b.z, b.w);
        Eb[i] = o;
    }
}

// ---------------------------------------------------------------------------
// Kernel 0b: W [K x N] fp32 -> WT [N x K] bf16 (transpose via LDS).
// ---------------------------------------------------------------------------
__global__ __launch_bounds__(256) void convert_WT_bf16(
    const float* __restrict__ W, short* __restrict__ WT, int K, int N)
{
    __shared__ float lds[32][33];
    const int tx = threadIdx.x & 31;
    const int ty = threadIdx.x >> 5;
    const int n0 = blockIdx.x * 32;
    const int k0 = blockIdx.y * 32;
#pragma unroll
    for (int i = 0; i < 4; ++i)
        lds[ty + 8 * i][tx] = W[(size_t)(k0 + ty + 8 * i) * N + n0 + tx];
    __syncthreads();
#pragma unroll
    for (int i = 0; i < 4; ++i)
        WT[(size_t)(n0 + ty + 8 * i) * K + k0 + tx] =
            (short)f2bf(lds[tx][ty + 8 * i]);
}

// ---------------------------------------------------------------------------
// Kernel 1a: embedding bag from fp8 table -> bf16 sent.
// One block per batch row, 4 waves; each wave reads whole 512B rows
// (64 lanes x 8B). HW fp8->f32 decode, fp32 accumulate, LDS reduce.
// ---------------------------------------------------------------------------
__global__ __launch_bounds__(256) void embed_mean_fp8(
    const int* __restrict__ idx, const unsigned char* __restrict__ Eb,
    unsigned int* __restrict__ sentB)
{
    __shared__ int sIdx[SEQ];
    __shared__ float red[3 * 512];
    const int b = blockIdx.x;
    const int t = threadIdx.x;
    if (t < SEQ) sIdx[t] = idx[b * SEQ + t];
    __syncthreads();

    const int g = t >> 6;      // wave id 0..3
    const int lane = t & 63;   // 8B chunk within row
    float acc[8] = {};

    for (int s = g; s < SEQ; s += 4) {
        const u32x2* row =
            reinterpret_cast<const u32x2*>(Eb + (size_t)sIdx[s] * EMB) + lane;
        u32x2 v = *row;
#if FP8_HW
        acc[0] += __builtin_amdgcn_cvt_f32_fp8(v.x, 0);
        acc[1] += __builtin_amdgcn_cvt_f32_fp8(v.x, 1);
        acc[2] += __builtin_amdgcn_cvt_f32_fp8(v.x, 2);
        acc[3] += __builtin_amdgcn_cvt_f32_fp8(v.x, 3);
        acc[4] += __builtin_amdgcn_cvt_f32_fp8(v.y, 0);
        acc[5] += __builtin_amdgcn_cvt_f32_fp8(v.y, 1);
        acc[6] += __builtin_amdgcn_cvt_f32_fp8(v.y, 2);
        acc[7] += __builtin_amdgcn_cvt_f32_fp8(v.y, 3);
#else
        acc[0] += fp8_dec_sw(v.x & 0xff);
        acc[1] += fp8_dec_sw((v.x >> 8) & 0xff);
        acc[2] += fp8_dec_sw((v.x >> 16) & 0xff);
        acc[3] += fp8_dec_sw(v.x >> 24);
        acc[4] += fp8_dec_sw(v.y & 0xff);
        acc[5] += fp8_dec_sw((v.y >> 8) & 0xff);
        acc[6] += fp8_dec_sw((v.y >> 16) & 0xff);
        acc[7] += fp8_dec_sw(v.y >> 24);
#endif
    }

    if (g) {
        float4* r = reinterpret_cast<float4*>(&red[(g - 1) * 512 + lane * 8]);
        r[0] = make_float4(acc[0], acc[1], acc[2], acc[3]);
        r[1] = make_float4(acc[4], acc[5], acc[6], acc[7]);
    }
    __syncthreads();
    if (g == 0) {
        const float sc = 1.0f / (float)SEQ;
        float o[8];
#pragma unroll
        for (int j = 0; j < 8; ++j)
            o[j] = (acc[j] + red[0 * 512 + lane * 8 + j] +
                    red[1 * 512 + lane * 8 + j] + red[2 * 512 + lane * 8 + j]) * sc;
        uint4 pk;
        pk.x = pack2(o[0], o[1]);
        pk.y = pack2(o[2], o[3]);
        pk.z = pack2(o[4], o[5]);
        pk.w = pack2(o[6], o[7]);
        reinterpret_cast<uint4*>(sentB + (size_t)b * 256)[lane] = pk;
    }
}

// ---------------------------------------------------------------------------
// Kernel 1b (fallback fp32 gather)
// ---------------------------------------------------------------------------
__global__ __launch_bounds__(256) void embed_mean_kernel(
    const int* __restrict__ idx, const float* __restrict__ E,
    float* __restrict__ sent)
{
    __shared__ int sIdx[SEQ];
    __shared__ float4 red[128];
    const int b = blockIdx.x;
    const int t = threadIdx.x;
    if (t < SEQ) sIdx[t] = idx[b * SEQ + t];
    __syncthreads();

    const int half = t >> 7;
    const int lane = t & 127;
    float4 acc = make_float4(0.f, 0.f, 0.f, 0.f);
    for (int s = half; s < SEQ; s += 2) {
        const float4* row =
            reinterpret_cast<const float4*>(E + (size_t)sIdx[s] * EMB);
        float4 v = row[lane];
        acc.x += v.x; acc.y += v.y; acc.z += v.z; acc.w += v.w;
    }
    if (half == 1) red[lane] = acc;
    __syncthreads();
    if (half == 0) {
        float4 o = red[lane];
        const float sc = 1.0f / (float)SEQ;
        float4 r;
        r.x = (acc.x + o.x) * sc;
        r.y = (acc.y + o.y) * sc;
        r.z = (acc.z + o.z) * sc;
        r.w = (acc.w + o.w) * sc;
        reinterpret_cast<float4*>(sent + (size_t)b * EMB)[lane] = r;
    }
}

// ---------------------------------------------------------------------------
// Kernel 2a: bf16 MFMA GEMM, C = relu(A @ B + bias).
// A: bf16 [M][K] row-major. BT: bf16 [N][K]. BM=128, BN=64, BK=32;
// 256 threads = 4 waves (2x2); wave computes 64x32 output.
// ---------------------------------------------------------------------------
template <int N, int K, bool OUT_BF16>
__global__ __launch_bounds__(256) void gemm_mfma_bias_relu(
    const short* __restrict__ A, const short* __restrict__ BT,
    const float* __restrict__ bias, void* __restrict__ C)
{
    constexpr int BM = 128, BN = 64, BK = 32;
    __shared__ float4 As[512];
    __shared__ float4 Bs[256];

    const int t = threadIdx.x;
    const int l = t & 63;
    const int w = t >> 6;
    const int wr = w >> 1;
    const int wc = w & 1;
    const int m0 = blockIdx.x * BM;
    const int n0 = blockIdx.y * BN;

    const int srow = (t >> 6) * 16 + (t & 15);
    const int skg = (t >> 4) & 3;

    f32x4 acc[4][2] = {};

    for (int kt = 0; kt < K; kt += BK) {
        const float4 a0 = *reinterpret_cast<const float4*>(
            A + (size_t)(m0 + srow) * K + kt + skg * 8);
        const float4 a1 = *reinterpret_cast<const float4*>(
            A + (size_t)(m0 + srow + 64) * K + kt + skg * 8);
        const float4 b0 = *reinterpret_cast<const float4*>(
            BT + (size_t)(n0 + srow) * K + kt + skg * 8);
        __syncthreads();
        As[t] = a0;
        As[t + 256] = a1;
        Bs[t] = b0;
        __syncthreads();

        bf16x8 afr[4], bfr[2];
#pragma unroll
        for (int f = 0; f < 4; ++f)
            afr[f] = *reinterpret_cast<const bf16x8*>(
                &As[(wr * 4 + f) * 64 + (l >> 4) * 16 + (l & 15)]);
#pragma unroll
        for (int g = 0; g < 2; ++g)
            bfr[g] = *reinterpret_cast<const bf16x8*>(
                &Bs[(wc * 2 + g) * 64 + (l >> 4) * 16 + (l & 15)]);
#pragma unroll
        for (int f = 0; f < 4; ++f)
#pragma unroll
            for (int g = 0; g < 2; ++g)
                acc[f][g] = __builtin_amdgcn_mfma_f32_16x16x32_bf16(
                    afr[f], bfr[g], acc[f][g], 0, 0, 0);
    }

#pragma unroll
    for (int g = 0; g < 2; ++g) {
        const int col = n0 + wc * 32 + g * 16 + (l & 15);
        const float bv = bias[col];
#pragma unroll
        for (int f = 0; f < 4; ++f) {
#pragma unroll
            for (int r = 0; r < 4; ++r) {
                const int row = m0 + wr * 64 + f * 16 + (l >> 4) * 4 + r;
                const float v = fmaxf(acc[f][g][r] + bv, 0.f);
                if (OUT_BF16)
                    ((short*)C)[(size_t)row * N + col] = (short)f2bf(v);
                else
                    ((float*)C)[(size_t)row * N + col] = v;
            }
        }
    }
}

// ---------------------------------------------------------------------------
// Kernel 2b: fp32 tiled GEMM, C = relu(A @ W + bias). (L3/L4 + fallback)
// ---------------------------------------------------------------------------
template <int N, int K>
__global__ __launch_bounds__(256) void gemm_bias_relu(
    const float* __restrict__ A, const float* __restrict__ W,
    const float* __restrict__ bias, float* __restrict__ C)
{
    constexpr int BM = 64, BN = 64, BK = 16, LDT = 68;
    __shared__ float As[BK][LDT];
    __shared__ float Bs[BK][LDT];

    const int t = threadIdx.x;
    const int m0 = blockIdx.x * BM;
    const int n0 = blockIdx.y * BN;

    const int arow = t >> 2;
    const int acg  = (t & 3) * 4;
    const int brow = t >> 4;
    const int bcg  = (t & 15) * 4;

    const int tr = (t >> 4) * 4;
    const int tc = (t & 15) * 4;

    float acc[4][4] = {};

    for (int kt = 0; kt < K; kt += BK) {
        float4 av = *reinterpret_cast<const float4*>(
            &A[(size_t)(m0 + arow) * K + kt + acg]);
        float4 bv = *reinterpret_cast<const float4*>(
            &W[(size_t)(kt + brow) * N + n0 + bcg]);
        __syncthreads();
        As[acg + 0][arow] = av.x;
        As[acg + 1][arow] = av.y;
        As[acg + 2][arow] = av.z;
        As[acg + 3][arow] = av.w;
        *reinterpret_cast<float4*>(&Bs[brow][bcg]) = bv;
        __syncthreads();
#pragma unroll
        for (int kk = 0; kk < BK; ++kk) {
            float4 a4 = *reinterpret_cast<const float4*>(&As[kk][tr]);
            float4 b4 = *reinterpret_cast<const float4*>(&Bs[kk][tc]);
            float aa[4] = {a4.x, a4.y, a4.z, a4.w};
            float bb[4] = {b4.x, b4.y, b4.z, b4.w};
#pragma unroll
            for (int i = 0; i < 4; ++i)
#pragma unroll
                for (int j = 0; j < 4; ++j)
                    acc[i][j] = fmaf(aa[i], bb[j], acc[i][j]);
        }
    }

    float4 bias4 = *reinterpret_cast<const float4*>(&bias[n0 + tc]);
    float bb[4] = {bias4.x, bias4.y, bias4.z, bias4.w};
#pragma unroll
    for (int i = 0; i < 4; ++i) {
        float4 r;
        r.x = fmaxf(acc[i][0] + bb[0], 0.f);
        r.y = fmaxf(acc[i][1] + bb[1], 0.f);
        r.z = fmaxf(acc[i][2] + bb[2], 0.f);
        r.w = fmaxf(acc[i][3] + bb[3], 0.f);
        *reinterpret_cast<float4*>(&C[(size_t)(m0 + tr + i) * N + n0 + tc]) = r;
    }
}

// ---------------------------------------------------------------------------
// Kernel 3: final layer (K=64, N=3) + softmax.
// ---------------------------------------------------------------------------
__global__ __launch_bounds__(256) void final_softmax_kernel(
    const float* __restrict__ h4, const float* __restrict__ W5,
    const float* __restrict__ b5, float* __restrict__ out)
{
    __shared__ float w[64 * 3];
    __shared__ float bb[3];
    const int t = threadIdx.x;
    if (t < 192) w[t] = W5[t];
    if (t < 3) bb[t] = b5[t];
    __syncthreads();

    const int row = blockIdx.x * 256 + t;
    float a0 = bb[0], a1 = bb[1], a2 = bb[2];
    const float* hr = h4 + (size_t)row * 64;
#pragma unroll
    for (int k = 0; k < 64; ++k) {
        float h = hr[k];
        a0 = fmaf(h, w[k * 3 + 0], a0);
        a1 = fmaf(h, w[k * 3 + 1], a1);
        a2 = fmaf(h, w[k * 3 + 2], a2);
    }
    float m  = fmaxf(a0, fmaxf(a1, a2));
    float e0 = expf(a0 - m), e1 = expf(a1 - m), e2 = expf(a2 - m);
    float inv = 1.0f / (e0 + e1 + e2);
    out[row * 3 + 0] = e0 * inv;
    out[row * 3 + 1] = e1 * inv;
    out[row * 3 + 2] = e2 * inv;
}

// ---------------------------------------------------------------------------
// Workspace layout (fp8 path), bytes:
//   Eb8   @ 0          : 51,200,000  (fp8 E)
//   W1T   @ 51,200,000 :    524,288
//   W2T   @ 51,724,288 :    262,144
//   sentB @ 51,986,432 :  4,194,304
//   h1B   @ 56,180,736 :  4,194,304
//   h2    @ 60,375,040 :  4,194,304
//   h3    @ 64,569,344 :  2,097,152
//   h4    @ 66,666,496 :  1,048,576   total 67,715,072
// ---------------------------------------------------------------------------
extern "C" void kernel_launch(void* const* d_in, const int* in_sizes, int n_in,
                              void* d_out, int out_size, void* d_ws,
                              size_t ws_size, hipStream_t stream)
{
    const int*   inputs = (const int*)d_in[0];
    const float* E  = (const float*)d_in[1];
    const float* W1 = (const float*)d_in[2];
    const float* b1 = (const float*)d_in[3];
    const float* W2 = (const float*)d_in[4];
    const float* b2 = (const float*)d_in[5];
    const float* W3 = (const float*)d_in[6];
    const float* b3 = (const float*)d_in[7];
    const float* W4 = (const float*)d_in[8];
    const float* b4 = (const float*)d_in[9];
    const float* W5 = (const float*)d_in[10];
    const float* b5 = (const float*)d_in[11];
    float* out = (float*)d_out;

    const size_t eb8Bytes = (size_t)VOCAB * EMB;  // 51,200,000
    const size_t needed = eb8Bytes + 524288 + 262144 + 3 * 4194304 + 2097152 + 1048576;

    if (ws_size >= needed) {
        char* p = (char*)d_ws;
        unsigned char* Eb8  = (unsigned char*)p;
        short*        W1T   = (short*)(p + eb8Bytes);
        short*        W2T   = (short*)(p + eb8Bytes + 524288);
        unsigned int* sentB = (unsigned int*)(p + eb8Bytes + 786432);
        short*        h1B   = (short*)(p + eb8Bytes + 786432 + 4194304);
        float*        h2    = (float*)(p + eb8Bytes + 786432 + 2 * 4194304);
        float*        h3    = (float*)(p + eb8Bytes + 786432 + 3 * 4194304);
        float*        h4    = (float*)(p + eb8Bytes + 786432 + 3 * 4194304 + 2097152);

        convert_WT_bf16<<<dim3(512 / 32, 512 / 32), 256, 0, stream>>>(W1, W1T, 512, 512);
        convert_WT_bf16<<<dim3(256 / 32, 512 / 32), 256, 0, stream>>>(W2, W2T, 512, 256);
        convert_E_fp8<<<2048, 256, 0, stream>>>(E, (u32x2*)Eb8, VOCAB * EMB / 8);
        embed_mean_fp8<<<BATCH, 256, 0, stream>>>(inputs, Eb8, sentB);

        gemm_mfma_bias_relu<512, 512, true>
            <<<dim3(BATCH / 128, 512 / 64), 256, 0, stream>>>(
                (const short*)sentB, W1T, b1, (void*)h1B);
        gemm_mfma_bias_relu<256, 512, false>
            <<<dim3(BATCH / 128, 256 / 64), 256, 0, stream>>>(
                h1B, W2T, b2, (void*)h2);
        gemm_bias_relu<128, 256><<<dim3(BATCH / 64, 2), 256, 0, stream>>>(
            h2, W3, b3, h3);
        gemm_bias_relu<64, 128><<<dim3(BATCH / 64, 1), 256, 0, stream>>>(
            h3, W4, b4, h4);
        final_softmax_kernel<<<BATCH / 256, 256, 0, stream>>>(h4, W5, b5, out);
    } else {
        float* act  = (float*)d_ws;
        float* sent = act;
        float* h1   = act + 2097152;
        float* h2   = act;
        float* h3   = act + 2097152;
        float* h4   = act;
        embed_mean_kernel<<<BATCH, 256, 0, stream>>>(inputs, E, sent);
        gemm_bias_relu<512, 512><<<dim3(BATCH / 64, 8), 256, 0, stream>>>(
            sent, W1, b1, h1);
        gemm_bias_relu<256, 512><<<dim3(BATCH / 64, 4), 256, 0, stream>>>(
            h1, W2, b2, h2);
        gemm_bias_relu<128, 256><<<dim3(BATCH / 64, 2), 256, 0, stream>>>(
            h2, W3, b3, h3);
        gemm_bias_relu<64, 128><<<dim3(BATCH / 64, 1), 256, 0, stream>>>(
            h3, W4, b4, h4);
        final_softmax_kernel<<<BATCH / 256, 256, 0, stream>>>(h4, W5, b5, out);
    }
}

// Round 6
// 155.899 us; speedup vs baseline: 1.4529x; 1.0919x over previous
//
#include <hip/hip_runtime.h>
#include <hip/hip_bf16.h>
#include <math.h>

#define BATCH 4096
#define SEQ 200
#define EMB 512
#define VOCAB 100000

typedef __attribute__((ext_vector_type(8))) short bf16x8;
typedef __attribute__((ext_vector_type(4))) float f32x4;
typedef __attribute__((ext_vector_type(2))) unsigned int u32x2;

// ---------------------------------------------------------------------------
// bf16 helpers
// ---------------------------------------------------------------------------
__device__ inline unsigned int f2bf(float f) {
    unsigned int u = __float_as_uint(f);
    return (u + 0x7FFFu + ((u >> 16) & 1u)) >> 16;
}
__device__ inline unsigned int pack2(float lo, float hi) {
    return f2bf(lo) | (f2bf(hi) << 16);
}

// ---------------------------------------------------------------------------
// fp8 e4m3 (OCP) encode/decode. Primary path: gfx950 hardware cvt builtins.
// ---------------------------------------------------------------------------
#if __has_builtin(__builtin_amdgcn_cvt_pk_fp8_f32) && __has_builtin(__builtin_amdgcn_cvt_f32_fp8)
#define FP8_HW 1
#else
#define FP8_HW 0
__device__ inline unsigned int fp8_enc_sw(float f) {
    unsigned int u = __float_as_uint(f);
    unsigned int s = u >> 31;
    u &= 0x7fffffffu;
    float a = __uint_as_float(u);
    if (a < 0.015625f) {
        unsigned int m = (unsigned int)(int)rintf(a * 512.0f);
        return (s << 7) | m;
    }
    if (a >= 448.0f) return (s << 7) | 0x7e;
    u += 0x7FFFFu + ((u >> 20) & 1u);
    unsigned int e = ((u >> 23) & 0xff) - 120u;
    unsigned int m = (u >> 20) & 7u;
    if (e > 15u || (e == 15u && m == 7u)) return (s << 7) | 0x7e;
    return (s << 7) | (e << 3) | m;
}
__device__ inline float fp8_dec_sw(unsigned int b) {
    unsigned int s = (b >> 7) & 1u, em = b & 0x7fu;
    float v;
    if (em >= 8u)
        v = __uint_as_float((((em >> 3) + 120u) << 23) | ((em & 7u) << 20));
    else
        v = (float)em * 0.001953125f;
    return s ? -v : v;
}
#endif

__device__ inline unsigned int fp8_pack4(float a, float b, float c, float d) {
#if FP8_HW
    int w = __builtin_amdgcn_cvt_pk_fp8_f32(a, b, 0, false);
    w = __builtin_amdgcn_cvt_pk_fp8_f32(c, d, w, true);
    return (unsigned int)w;
#else
    return fp8_enc_sw(a) | (fp8_enc_sw(b) << 8) | (fp8_enc_sw(c) << 16) |
           (fp8_enc_sw(d) << 24);
#endif
}

// ---------------------------------------------------------------------------
// Kernel 0a: convert E (fp32 [VOCAB x EMB]) -> fp8 e4m3 table (51.2 MB).
// Non-temporal reads of E keep the fp8 table L3-resident for the gather.
// ---------------------------------------------------------------------------
__global__ __launch_bounds__(256) void convert_E_fp8(
    const float* __restrict__ E, u32x2* __restrict__ Eb, int n8)
{
    const int stride = gridDim.x * 256;
    for (int i = blockIdx.x * 256 + threadIdx.x; i < n8; i += stride) {
        const f32x4* p = reinterpret_cast<const f32x4*>(E) + (size_t)i * 2;
        f32x4 a = __builtin_nontemporal_load(p);
        f32x4 b = __builtin_nontemporal_load(p + 1);
        u32x2 o;
        o.x = fp8_pack4(a.x, a.y, a.z, a.w);
        o.y = fp8_pack4(b.x, b.y, b.z, b.w);
        Eb[i] = o;
    }
}

// ---------------------------------------------------------------------------
// Kernel 0b: fused transpose+convert of W1..W4 (fp32 [K][N] -> bf16 [N][K]).
// One launch; blocks partitioned by matrix. 32x32 tile via LDS.
//   W1 512x512: 256 blocks | W2 512x256: 128 | W3 256x128: 32 | W4 128x64: 8
// ---------------------------------------------------------------------------
struct WT4Args {
    const float *s0, *s1, *s2, *s3;
    short *d0, *d1, *d2, *d3;
};

__global__ __launch_bounds__(256) void convert_WT4(WT4Args a)
{
    __shared__ float lds[32][33];
    const int bid = blockIdx.x;
    const float* src;
    short* dst;
    int K, N, local;
    if (bid < 256)      { src = a.s0; dst = a.d0; K = 512; N = 512; local = bid; }
    else if (bid < 384) { src = a.s1; dst = a.d1; K = 512; N = 256; local = bid - 256; }
    else if (bid < 416) { src = a.s2; dst = a.d2; K = 256; N = 128; local = bid - 384; }
    else                { src = a.s3; dst = a.d3; K = 128; N = 64;  local = bid - 416; }
    const int nbn = N >> 5;
    const int n0 = (local % nbn) * 32;
    const int k0 = (local / nbn) * 32;
    const int tx = threadIdx.x & 31;
    const int ty = threadIdx.x >> 5;
#pragma unroll
    for (int i = 0; i < 4; ++i)
        lds[ty + 8 * i][tx] = src[(size_t)(k0 + ty + 8 * i) * N + n0 + tx];
    __syncthreads();
#pragma unroll
    for (int i = 0; i < 4; ++i)
        dst[(size_t)(n0 + ty + 8 * i) * K + k0 + tx] =
            (short)f2bf(lds[tx][ty + 8 * i]);
}

// ---------------------------------------------------------------------------
// Kernel 1a: embedding bag from fp8 table -> bf16 sent.
// One block per batch row, 4 waves; each wave reads whole 512B rows
// (64 lanes x 8B). HW fp8->f32 decode, fp32 accumulate, LDS reduce.
// ---------------------------------------------------------------------------
__global__ __launch_bounds__(256) void embed_mean_fp8(
    const int* __restrict__ idx, const unsigned char* __restrict__ Eb,
    unsigned int* __restrict__ sentB)
{
    __shared__ int sIdx[SEQ];
    __shared__ float red[3 * 512];
    const int b = blockIdx.x;
    const int t = threadIdx.x;
    if (t < SEQ) sIdx[t] = idx[b * SEQ + t];
    __syncthreads();

    const int g = t >> 6;
    const int lane = t & 63;
    float acc[8] = {};

    for (int s = g; s < SEQ; s += 4) {
        const u32x2* row =
            reinterpret_cast<const u32x2*>(Eb + (size_t)sIdx[s] * EMB) + lane;
        u32x2 v = *row;
#if FP8_HW
        acc[0] += __builtin_amdgcn_cvt_f32_fp8(v.x, 0);
        acc[1] += __builtin_amdgcn_cvt_f32_fp8(v.x, 1);
        acc[2] += __builtin_amdgcn_cvt_f32_fp8(v.x, 2);
        acc[3] += __builtin_amdgcn_cvt_f32_fp8(v.x, 3);
        acc[4] += __builtin_amdgcn_cvt_f32_fp8(v.y, 0);
        acc[5] += __builtin_amdgcn_cvt_f32_fp8(v.y, 1);
        acc[6] += __builtin_amdgcn_cvt_f32_fp8(v.y, 2);
        acc[7] += __builtin_amdgcn_cvt_f32_fp8(v.y, 3);
#else
        acc[0] += fp8_dec_sw(v.x & 0xff);
        acc[1] += fp8_dec_sw((v.x >> 8) & 0xff);
        acc[2] += fp8_dec_sw((v.x >> 16) & 0xff);
        acc[3] += fp8_dec_sw(v.x >> 24);
        acc[4] += fp8_dec_sw(v.y & 0xff);
        acc[5] += fp8_dec_sw((v.y >> 8) & 0xff);
        acc[6] += fp8_dec_sw((v.y >> 16) & 0xff);
        acc[7] += fp8_dec_sw(v.y >> 24);
#endif
    }

    if (g) {
        float4* r = reinterpret_cast<float4*>(&red[(g - 1) * 512 + lane * 8]);
        r[0] = make_float4(acc[0], acc[1], acc[2], acc[3]);
        r[1] = make_float4(acc[4], acc[5], acc[6], acc[7]);
    }
    __syncthreads();
    if (g == 0) {
        const float sc = 1.0f / (float)SEQ;
        float o[8];
#pragma unroll
        for (int j = 0; j < 8; ++j)
            o[j] = (acc[j] + red[0 * 512 + lane * 8 + j] +
                    red[1 * 512 + lane * 8 + j] + red[2 * 512 + lane * 8 + j]) * sc;
        uint4 pk;
        pk.x = pack2(o[0], o[1]);
        pk.y = pack2(o[2], o[3]);
        pk.z = pack2(o[4], o[5]);
        pk.w = pack2(o[6], o[7]);
        reinterpret_cast<uint4*>(sentB + (size_t)b * 256)[lane] = pk;
    }
}

// ---------------------------------------------------------------------------
// Kernel 1b (fallback fp32 gather)
// ---------------------------------------------------------------------------
__global__ __launch_bounds__(256) void embed_mean_kernel(
    const int* __restrict__ idx, const float* __restrict__ E,
    float* __restrict__ sent)
{
    __shared__ int sIdx[SEQ];
    __shared__ float4 red[128];
    const int b = blockIdx.x;
    const int t = threadIdx.x;
    if (t < SEQ) sIdx[t] = idx[b * SEQ + t];
    __syncthreads();

    const int half = t >> 7;
    const int lane = t & 127;
    float4 acc = make_float4(0.f, 0.f, 0.f, 0.f);
    for (int s = half; s < SEQ; s += 2) {
        const float4* row =
            reinterpret_cast<const float4*>(E + (size_t)sIdx[s] * EMB);
        float4 v = row[lane];
        acc.x += v.x; acc.y += v.y; acc.z += v.z; acc.w += v.w;
    }
    if (half == 1) red[lane] = acc;
    __syncthreads();
    if (half == 0) {
        float4 o = red[lane];
        const float sc = 1.0f / (float)SEQ;
        float4 r;
        r.x = (acc.x + o.x) * sc;
        r.y = (acc.y + o.y) * sc;
        r.z = (acc.z + o.z) * sc;
        r.w = (acc.w + o.w) * sc;
        reinterpret_cast<float4*>(sent + (size_t)b * EMB)[lane] = r;
    }
}

// ---------------------------------------------------------------------------
// Kernel 2a: bf16 MFMA GEMM, C = relu(A @ B + bias).
// A: bf16 [M][K] row-major. BT: bf16 [N][K]. BM=128, BN=64, BK=32;
// 256 threads = 4 waves (2x2); wave computes 64x32 output.
// ---------------------------------------------------------------------------
template <int N, int K, bool OUT_BF16>
__global__ __launch_bounds__(256) void gemm_mfma_bias_relu(
    const short* __restrict__ A, const short* __restrict__ BT,
    const float* __restrict__ bias, void* __restrict__ C)
{
    constexpr int BM = 128, BK = 32;
    (void)BM; (void)BK;
    __shared__ float4 As[512];
    __shared__ float4 Bs[256];

    const int t = threadIdx.x;
    const int l = t & 63;
    const int w = t >> 6;
    const int wr = w >> 1;
    const int wc = w & 1;
    const int m0 = blockIdx.x * 128;
    const int n0 = blockIdx.y * 64;

    const int srow = (t >> 6) * 16 + (t & 15);
    const int skg = (t >> 4) & 3;

    f32x4 acc[4][2] = {};

    for (int kt = 0; kt < K; kt += 32) {
        const float4 a0 = *reinterpret_cast<const float4*>(
            A + (size_t)(m0 + srow) * K + kt + skg * 8);
        const float4 a1 = *reinterpret_cast<const float4*>(
            A + (size_t)(m0 + srow + 64) * K + kt + skg * 8);
        const float4 b0 = *reinterpret_cast<const float4*>(
            BT + (size_t)(n0 + srow) * K + kt + skg * 8);
        __syncthreads();
        As[t] = a0;
        As[t + 256] = a1;
        Bs[t] = b0;
        __syncthreads();

        bf16x8 afr[4], bfr[2];
#pragma unroll
        for (int f = 0; f < 4; ++f)
            afr[f] = *reinterpret_cast<const bf16x8*>(
                &As[(wr * 4 + f) * 64 + (l >> 4) * 16 + (l & 15)]);
#pragma unroll
        for (int g = 0; g < 2; ++g)
            bfr[g] = *reinterpret_cast<const bf16x8*>(
                &Bs[(wc * 2 + g) * 64 + (l >> 4) * 16 + (l & 15)]);
#pragma unroll
        for (int f = 0; f < 4; ++f)
#pragma unroll
            for (int g = 0; g < 2; ++g)
                acc[f][g] = __builtin_amdgcn_mfma_f32_16x16x32_bf16(
                    afr[f], bfr[g], acc[f][g], 0, 0, 0);
    }

#pragma unroll
    for (int g = 0; g < 2; ++g) {
        const int col = n0 + wc * 32 + g * 16 + (l & 15);
        const float bv = bias[col];
#pragma unroll
        for (int f = 0; f < 4; ++f) {
#pragma unroll
            for (int r = 0; r < 4; ++r) {
                const int row = m0 + wr * 64 + f * 16 + (l >> 4) * 4 + r;
                const float v = fmaxf(acc[f][g][r] + bv, 0.f);
                if (OUT_BF16)
                    ((short*)C)[(size_t)row * N + col] = (short)f2bf(v);
                else
                    ((float*)C)[(size_t)row * N + col] = v;
            }
        }
    }
}

// ---------------------------------------------------------------------------
// Kernel 2b: fp32 tiled GEMM (fallback path only).
// ---------------------------------------------------------------------------
template <int N, int K>
__global__ __launch_bounds__(256) void gemm_bias_relu(
    const float* __restrict__ A, const float* __restrict__ W,
    const float* __restrict__ bias, float* __restrict__ C)
{
    constexpr int BK = 16, LDT = 68;
    __shared__ float As[BK][LDT];
    __shared__ float Bs[BK][LDT];

    const int t = threadIdx.x;
    const int m0 = blockIdx.x * 64;
    const int n0 = blockIdx.y * 64;

    const int arow = t >> 2;
    const int acg  = (t & 3) * 4;
    const int brow = t >> 4;
    const int bcg  = (t & 15) * 4;

    const int tr = (t >> 4) * 4;
    const int tc = (t & 15) * 4;

    float acc[4][4] = {};

    for (int kt = 0; kt < K; kt += BK) {
        float4 av = *reinterpret_cast<const float4*>(
            &A[(size_t)(m0 + arow) * K + kt + acg]);
        float4 bv = *reinterpret_cast<const float4*>(
            &W[(size_t)(kt + brow) * N + n0 + bcg]);
        __syncthreads();
        As[acg + 0][arow] = av.x;
        As[acg + 1][arow] = av.y;
        As[acg + 2][arow] = av.z;
        As[acg + 3][arow] = av.w;
        *reinterpret_cast<float4*>(&Bs[brow][bcg]) = bv;
        __syncthreads();
#pragma unroll
        for (int kk = 0; kk < BK; ++kk) {
            float4 a4 = *reinterpret_cast<const float4*>(&As[kk][tr]);
            float4 b4 = *reinterpret_cast<const float4*>(&Bs[kk][tc]);
            float aa[4] = {a4.x, a4.y, a4.z, a4.w};
            float bb[4] = {b4.x, b4.y, b4.z, b4.w};
#pragma unroll
            for (int i = 0; i < 4; ++i)
#pragma unroll
                for (int j = 0; j < 4; ++j)
                    acc[i][j] = fmaf(aa[i], bb[j], acc[i][j]);
        }
    }

    float4 bias4 = *reinterpret_cast<const float4*>(&bias[n0 + tc]);
    float bb[4] = {bias4.x, bias4.y, bias4.z, bias4.w};
#pragma unroll
    for (int i = 0; i < 4; ++i) {
        float4 r;
        r.x = fmaxf(acc[i][0] + bb[0], 0.f);
        r.y = fmaxf(acc[i][1] + bb[1], 0.f);
        r.z = fmaxf(acc[i][2] + bb[2], 0.f);
        r.w = fmaxf(acc[i][3] + bb[3], 0.f);
        *reinterpret_cast<float4*>(&C[(size_t)(m0 + tr + i) * N + n0 + tc]) = r;
    }
}

// ---------------------------------------------------------------------------
// Kernel 3: final layer (K=64, N=3) + softmax. One thread per batch row.
// ---------------------------------------------------------------------------
__global__ __launch_bounds__(256) void final_softmax_kernel(
    const float* __restrict__ h4, const float* __restrict__ W5,
    const float* __restrict__ b5, float* __restrict__ out)
{
    __shared__ float w[64 * 3];
    __shared__ float bb[3];
    const int t = threadIdx.x;
    if (t < 192) w[t] = W5[t];
    if (t < 3) bb[t] = b5[t];
    __syncthreads();

    const int row = blockIdx.x * 256 + t;
    float a0 = bb[0], a1 = bb[1], a2 = bb[2];
    const float* hr = h4 + (size_t)row * 64;
#pragma unroll
    for (int k = 0; k < 64; ++k) {
        float h = hr[k];
        a0 = fmaf(h, w[k * 3 + 0], a0);
        a1 = fmaf(h, w[k * 3 + 1], a1);
        a2 = fmaf(h, w[k * 3 + 2], a2);
    }
    float m  = fmaxf(a0, fmaxf(a1, a2));
    float e0 = expf(a0 - m), e1 = expf(a1 - m), e2 = expf(a2 - m);
    float inv = 1.0f / (e0 + e1 + e2);
    out[row * 3 + 0] = e0 * inv;
    out[row * 3 + 1] = e1 * inv;
    out[row * 3 + 2] = e2 * inv;
}

// ---------------------------------------------------------------------------
// Workspace layout (fp8 path), bytes:
//   Eb8   @ 0          : 51,200,000  (fp8 E)
//   W1T   @ 51,200,000 :    524,288  (bf16 [512][512])
//   W2T   @ 51,724,288 :    262,144  (bf16 [256][512])
//   W3T   @ 51,986,432 :     65,536  (bf16 [128][256])
//   W4T   @ 52,051,968 :     16,384  (bf16 [64][128])
//   sentB @ 52,068,352 :  4,194,304  (bf16 [4096][512])
//   h1B   @ 56,262,656 :  4,194,304  (bf16 [4096][512])
//   h2B   @ 60,456,960 :  2,097,152  (bf16 [4096][256])
//   h3B   @ 62,554,112 :  1,048,576  (bf16 [4096][128])
//   h4    @ 63,602,688 :  1,048,576  (f32  [4096][64])   total 64,651,264
// ---------------------------------------------------------------------------
extern "C" void kernel_launch(void* const* d_in, const int* in_sizes, int n_in,
                              void* d_out, int out_size, void* d_ws,
                              size_t ws_size, hipStream_t stream)
{
    const int*   inputs = (const int*)d_in[0];
    const float* E  = (const float*)d_in[1];
    const float* W1 = (const float*)d_in[2];
    const float* b1 = (const float*)d_in[3];
    const float* W2 = (const float*)d_in[4];
    const float* b2 = (const float*)d_in[5];
    const float* W3 = (const float*)d_in[6];
    const float* b3 = (const float*)d_in[7];
    const float* W4 = (const float*)d_in[8];
    const float* b4 = (const float*)d_in[9];
    const float* W5 = (const float*)d_in[10];
    const float* b5 = (const float*)d_in[11];
    float* out = (float*)d_out;

    const size_t eb8Bytes = (size_t)VOCAB * EMB;  // 51,200,000
    const size_t needed = 64651264;

    if (ws_size >= needed) {
        char* p = (char*)d_ws;
        unsigned char* Eb8  = (unsigned char*)p;
        short*        W1T   = (short*)(p + eb8Bytes);
        short*        W2T   = (short*)(p + eb8Bytes + 524288);
        short*        W3T   = (short*)(p + eb8Bytes + 786432);
        short*        W4T   = (short*)(p + eb8Bytes + 851968);
        unsigned int* sentB = (unsigned int*)(p + eb8Bytes + 868352);
        short*        h1B   = (short*)(p + eb8Bytes + 868352 + 4194304);
        short*        h2B   = (short*)(p + eb8Bytes + 868352 + 2 * 4194304);
        short*        h3B   = (short*)(p + eb8Bytes + 868352 + 2 * 4194304 + 2097152);
        float*        h4    = (float*)(p + eb8Bytes + 868352 + 2 * 4194304 + 3145728);

        WT4Args wa = {W1, W2, W3, W4, W1T, W2T, W3T, W4T};
        convert_WT4<<<424, 256, 0, stream>>>(wa);
        convert_E_fp8<<<2048, 256, 0, stream>>>(E, (u32x2*)Eb8, VOCAB * EMB / 8);
        embed_mean_fp8<<<BATCH, 256, 0, stream>>>(inputs, Eb8, sentB);

        gemm_mfma_bias_relu<512, 512, true>
            <<<dim3(BATCH / 128, 8), 256, 0, stream>>>(
                (const short*)sentB, W1T, b1, (void*)h1B);
        gemm_mfma_bias_relu<256, 512, true>
            <<<dim3(BATCH / 128, 4), 256, 0, stream>>>(
                h1B, W2T, b2, (void*)h2B);
        gemm_mfma_bias_relu<128, 256, true>
            <<<dim3(BATCH / 128, 2), 256, 0, stream>>>(
                h2B, W3T, b3, (void*)h3B);
        gemm_mfma_bias_relu<64, 128, false>
            <<<dim3(BATCH / 128, 1), 256, 0, stream>>>(
                h3B, W4T, b4, (void*)h4);
        final_softmax_kernel<<<BATCH / 256, 256, 0, stream>>>(h4, W5, b5, out);
    } else {
        float* act  = (float*)d_ws;
        float* sent = act;
        float* h1   = act + 2097152;
        float* h2   = act;
        float* h3   = act + 2097152;
        float* h4   = act;
        embed_mean_kernel<<<BATCH, 256, 0, stream>>>(inputs, E, sent);
        gemm_bias_relu<512, 512><<<dim3(BATCH / 64, 8), 256, 0, stream>>>(
            sent, W1, b1, h1);
        gemm_bias_relu<256, 512><<<dim3(BATCH / 64, 4), 256, 0, stream>>>(
            h1, W2, b2, h2);
        gemm_bias_relu<128, 256><<<dim3(BATCH / 64, 2), 256, 0, stream>>>(
            h2, W3, b3, h3);
        gemm_bias_relu<64, 128><<<dim3(BATCH / 64, 1), 256, 0, stream>>>(
            h3, W4, b4, h4);
        final_softmax_kernel<<<BATCH / 256, 256, 0, stream>>>(h4, W5, b5, out);
    }
}

// Round 7
// 145.344 us; speedup vs baseline: 1.5584x; 1.0726x over previous
//
#include <hip/hip_runtime.h>
#include <hip/hip_bf16.h>
#include <math.h>

#define BATCH 4096
#define SEQ 200
#define EMB 512
#define VOCAB 100000

typedef __attribute__((ext_vector_type(8))) short bf16x8;
typedef __attribute__((ext_vector_type(4))) float f32x4;
typedef __attribute__((ext_vector_type(2))) unsigned int u32x2;

// ---------------------------------------------------------------------------
// bf16 helpers
// ---------------------------------------------------------------------------
__device__ inline unsigned int f2bf(float f) {
    unsigned int u = __float_as_uint(f);
    return (u + 0x7FFFu + ((u >> 16) & 1u)) >> 16;
}
__device__ inline unsigned int pack2(float lo, float hi) {
    return f2bf(lo) | (f2bf(hi) << 16);
}

// ---------------------------------------------------------------------------
// fp8 e4m3 (OCP) encode/decode. Primary path: gfx950 hardware cvt builtins.
// ---------------------------------------------------------------------------
#if __has_builtin(__builtin_amdgcn_cvt_pk_fp8_f32) && __has_builtin(__builtin_amdgcn_cvt_f32_fp8)
#define FP8_HW 1
#else
#define FP8_HW 0
__device__ inline unsigned int fp8_enc_sw(float f) {
    unsigned int u = __float_as_uint(f);
    unsigned int s = u >> 31;
    u &= 0x7fffffffu;
    float a = __uint_as_float(u);
    if (a < 0.015625f) {
        unsigned int m = (unsigned int)(int)rintf(a * 512.0f);
        return (s << 7) | m;
    }
    if (a >= 448.0f) return (s << 7) | 0x7e;
    u += 0x7FFFFu + ((u >> 20) & 1u);
    unsigned int e = ((u >> 23) & 0xff) - 120u;
    unsigned int m = (u >> 20) & 7u;
    if (e > 15u || (e == 15u && m == 7u)) return (s << 7) | 0x7e;
    return (s << 7) | (e << 3) | m;
}
__device__ inline float fp8_dec_sw(unsigned int b) {
    unsigned int s = (b >> 7) & 1u, em = b & 0x7fu;
    float v;
    if (em >= 8u)
        v = __uint_as_float((((em >> 3) + 120u) << 23) | ((em & 7u) << 20));
    else
        v = (float)em * 0.001953125f;
    return s ? -v : v;
}
#endif

__device__ inline unsigned int fp8_pack4(float a, float b, float c, float d) {
#if FP8_HW
    int w = __builtin_amdgcn_cvt_pk_fp8_f32(a, b, 0, false);
    w = __builtin_amdgcn_cvt_pk_fp8_f32(c, d, w, true);
    return (unsigned int)w;
#else
    return fp8_enc_sw(a) | (fp8_enc_sw(b) << 8) | (fp8_enc_sw(c) << 16) |
           (fp8_enc_sw(d) << 24);
#endif
}

// ---------------------------------------------------------------------------
// Kernel 0: fused conversions, one launch.
//   blocks [0, 2048)    : E fp32 -> fp8 e4m3 table (grid-stride, nt loads)
//   blocks [2048, 2472) : W1..W4 fp32 [K][N] -> bf16 [N][K] (32x32 LDS tiles)
// ---------------------------------------------------------------------------
struct ConvArgs {
    const float* E;
    u32x2* Eb;
    int n8;
    const float *s0, *s1, *s2, *s3;
    short *d0, *d1, *d2, *d3;
};

__global__ __launch_bounds__(256) void convert_all(ConvArgs a)
{
    const int bid = blockIdx.x;
    if (bid < 2048) {
        const int stride = 2048 * 256;
        for (int i = bid * 256 + threadIdx.x; i < a.n8; i += stride) {
            const f32x4* p = reinterpret_cast<const f32x4*>(a.E) + (size_t)i * 2;
            f32x4 x = __builtin_nontemporal_load(p);
            f32x4 y = __builtin_nontemporal_load(p + 1);
            u32x2 o;
            o.x = fp8_pack4(x.x, x.y, x.z, x.w);
            o.y = fp8_pack4(y.x, y.y, y.z, y.w);
            a.Eb[i] = o;
        }
        return;
    }
    __shared__ float lds[32][33];
    const int wb = bid - 2048;
    const float* src;
    short* dst;
    int K, N, local;
    if (wb < 256)      { src = a.s0; dst = a.d0; K = 512; N = 512; local = wb; }
    else if (wb < 384) { src = a.s1; dst = a.d1; K = 512; N = 256; local = wb - 256; }
    else if (wb < 416) { src = a.s2; dst = a.d2; K = 256; N = 128; local = wb - 384; }
    else               { src = a.s3; dst = a.d3; K = 128; N = 64;  local = wb - 416; }
    const int nbn = N >> 5;
    const int n0 = (local % nbn) * 32;
    const int k0 = (local / nbn) * 32;
    const int tx = threadIdx.x & 31;
    const int ty = threadIdx.x >> 5;
#pragma unroll
    for (int i = 0; i < 4; ++i)
        lds[ty + 8 * i][tx] = src[(size_t)(k0 + ty + 8 * i) * N + n0 + tx];
    __syncthreads();
#pragma unroll
    for (int i = 0; i < 4; ++i)
        dst[(size_t)(n0 + ty + 8 * i) * K + k0 + tx] =
            (short)f2bf(lds[tx][ty + 8 * i]);
}

// ---------------------------------------------------------------------------
// Kernel 1a: embedding bag from fp8 table -> bf16 sent.
// One block per batch row, 4 waves; wave reads whole 512B rows (64 x 8B).
// ---------------------------------------------------------------------------
__global__ __launch_bounds__(256) void embed_mean_fp8(
    const int* __restrict__ idx, const unsigned char* __restrict__ Eb,
    unsigned int* __restrict__ sentB)
{
    __shared__ int sIdx[SEQ];
    __shared__ float red[3 * 512];
    const int b = blockIdx.x;
    const int t = threadIdx.x;
    if (t < SEQ) sIdx[t] = idx[b * SEQ + t];
    __syncthreads();

    const int g = t >> 6;
    const int lane = t & 63;
    float acc[8] = {};

    for (int s = g; s < SEQ; s += 4) {
        const u32x2* row =
            reinterpret_cast<const u32x2*>(Eb + (size_t)sIdx[s] * EMB) + lane;
        u32x2 v = *row;
#if FP8_HW
        acc[0] += __builtin_amdgcn_cvt_f32_fp8(v.x, 0);
        acc[1] += __builtin_amdgcn_cvt_f32_fp8(v.x, 1);
        acc[2] += __builtin_amdgcn_cvt_f32_fp8(v.x, 2);
        acc[3] += __builtin_amdgcn_cvt_f32_fp8(v.x, 3);
        acc[4] += __builtin_amdgcn_cvt_f32_fp8(v.y, 0);
        acc[5] += __builtin_amdgcn_cvt_f32_fp8(v.y, 1);
        acc[6] += __builtin_amdgcn_cvt_f32_fp8(v.y, 2);
        acc[7] += __builtin_amdgcn_cvt_f32_fp8(v.y, 3);
#else
        acc[0] += fp8_dec_sw(v.x & 0xff);
        acc[1] += fp8_dec_sw((v.x >> 8) & 0xff);
        acc[2] += fp8_dec_sw((v.x >> 16) & 0xff);
        acc[3] += fp8_dec_sw(v.x >> 24);
        acc[4] += fp8_dec_sw(v.y & 0xff);
        acc[5] += fp8_dec_sw((v.y >> 8) & 0xff);
        acc[6] += fp8_dec_sw((v.y >> 16) & 0xff);
        acc[7] += fp8_dec_sw(v.y >> 24);
#endif
    }

    if (g) {
        float4* r = reinterpret_cast<float4*>(&red[(g - 1) * 512 + lane * 8]);
        r[0] = make_float4(acc[0], acc[1], acc[2], acc[3]);
        r[1] = make_float4(acc[4], acc[5], acc[6], acc[7]);
    }
    __syncthreads();
    if (g == 0) {
        const float sc = 1.0f / (float)SEQ;
        float o[8];
#pragma unroll
        for (int j = 0; j < 8; ++j)
            o[j] = (acc[j] + red[0 * 512 + lane * 8 + j] +
                    red[1 * 512 + lane * 8 + j] + red[2 * 512 + lane * 8 + j]) * sc;
        uint4 pk;
        pk.x = pack2(o[0], o[1]);
        pk.y = pack2(o[2], o[3]);
        pk.z = pack2(o[4], o[5]);
        pk.w = pack2(o[6], o[7]);
        reinterpret_cast<uint4*>(sentB + (size_t)b * 256)[lane] = pk;
    }
}

// ---------------------------------------------------------------------------
// Kernel 1b (fallback fp32 gather)
// ---------------------------------------------------------------------------
__global__ __launch_bounds__(256) void embed_mean_kernel(
    const int* __restrict__ idx, const float* __restrict__ E,
    float* __restrict__ sent)
{
    __shared__ int sIdx[SEQ];
    __shared__ float4 red[128];
    const int b = blockIdx.x;
    const int t = threadIdx.x;
    if (t < SEQ) sIdx[t] = idx[b * SEQ + t];
    __syncthreads();

    const int half = t >> 7;
    const int lane = t & 127;
    float4 acc = make_float4(0.f, 0.f, 0.f, 0.f);
    for (int s = half; s < SEQ; s += 2) {
        const float4* row =
            reinterpret_cast<const float4*>(E + (size_t)sIdx[s] * EMB);
        float4 v = row[lane];
        acc.x += v.x; acc.y += v.y; acc.z += v.z; acc.w += v.w;
    }
    if (half == 1) red[lane] = acc;
    __syncthreads();
    if (half == 0) {
        float4 o = red[lane];
        const float sc = 1.0f / (float)SEQ;
        float4 r;
        r.x = (acc.x + o.x) * sc;
        r.y = (acc.y + o.y) * sc;
        r.z = (acc.z + o.z) * sc;
        r.w = (acc.w + o.w) * sc;
        reinterpret_cast<float4*>(sent + (size_t)b * EMB)[lane] = r;
    }
}

// ---------------------------------------------------------------------------
// Kernel 2a: bf16 MFMA GEMM, C = relu(A @ B + bias). (L1, L2)
// ---------------------------------------------------------------------------
template <int N, int K, bool OUT_BF16>
__global__ __launch_bounds__(256) void gemm_mfma_bias_relu(
    const short* __restrict__ A, const short* __restrict__ BT,
    const float* __restrict__ bias, void* __restrict__ C)
{
    __shared__ float4 As[512];
    __shared__ float4 Bs[256];

    const int t = threadIdx.x;
    const int l = t & 63;
    const int w = t >> 6;
    const int wr = w >> 1;
    const int wc = w & 1;
    const int m0 = blockIdx.x * 128;
    const int n0 = blockIdx.y * 64;

    const int srow = (t >> 6) * 16 + (t & 15);
    const int skg = (t >> 4) & 3;

    f32x4 acc[4][2] = {};

    for (int kt = 0; kt < K; kt += 32) {
        const float4 a0 = *reinterpret_cast<const float4*>(
            A + (size_t)(m0 + srow) * K + kt + skg * 8);
        const float4 a1 = *reinterpret_cast<const float4*>(
            A + (size_t)(m0 + srow + 64) * K + kt + skg * 8);
        const float4 b0 = *reinterpret_cast<const float4*>(
            BT + (size_t)(n0 + srow) * K + kt + skg * 8);
        __syncthreads();
        As[t] = a0;
        As[t + 256] = a1;
        Bs[t] = b0;
        __syncthreads();

        bf16x8 afr[4], bfr[2];
#pragma unroll
        for (int f = 0; f < 4; ++f)
            afr[f] = *reinterpret_cast<const bf16x8*>(
                &As[(wr * 4 + f) * 64 + (l >> 4) * 16 + (l & 15)]);
#pragma unroll
        for (int g = 0; g < 2; ++g)
            bfr[g] = *reinterpret_cast<const bf16x8*>(
                &Bs[(wc * 2 + g) * 64 + (l >> 4) * 16 + (l & 15)]);
#pragma unroll
        for (int f = 0; f < 4; ++f)
#pragma unroll
            for (int g = 0; g < 2; ++g)
                acc[f][g] = __builtin_amdgcn_mfma_f32_16x16x32_bf16(
                    afr[f], bfr[g], acc[f][g], 0, 0, 0);
    }

#pragma unroll
    for (int g = 0; g < 2; ++g) {
        const int col = n0 + wc * 32 + g * 16 + (l & 15);
        const float bv = bias[col];
#pragma unroll
        for (int f = 0; f < 4; ++f) {
#pragma unroll
            for (int r = 0; r < 4; ++r) {
                const int row = m0 + wr * 64 + f * 16 + (l >> 4) * 4 + r;
                const float v = fmaxf(acc[f][g][r] + bv, 0.f);
                if (OUT_BF16)
                    ((short*)C)[(size_t)row * N + col] = (short)f2bf(v);
                else
                    ((float*)C)[(size_t)row * N + col] = v;
            }
        }
    }
}

// ---------------------------------------------------------------------------
// Kernel 2c: fused tail — h3 = relu(h2 @ W3), h4 = relu(h3 @ W4),
// out = softmax(h4 @ W5 + b5). One block = 64 batch rows, 4 waves (2x2).
// All intermediates LDS-resident; row-major LDS A-tiles XOR-swizzled
// (byte ^= (row&7)<<4) to break the D-stride bank conflict.
// ---------------------------------------------------------------------------
__global__ __launch_bounds__(256) void mlp_tail(
    const short* __restrict__ h2B,   // bf16 [4096][256]
    const short* __restrict__ W3T,   // bf16 [128][256]
    const float* __restrict__ b3,
    const short* __restrict__ W4T,   // bf16 [64][128]
    const float* __restrict__ b4,
    const float* __restrict__ W5,    // f32 [64][3]
    const float* __restrict__ b5,
    float* __restrict__ out)
{
    __shared__ char buf0[32768];     // h2 tile (bf16 64x256 swz) then h4 (f32 [64][65])
    __shared__ char h3buf[16384];    // h3 (bf16 64x128 swz)
    __shared__ float4 Bs[512];
    __shared__ float w5s[192];
    __shared__ float b5s[3];

    const int t = threadIdx.x;
    const int l = t & 63;
    const int w = t >> 6;
    const int wr = w >> 1;   // 32-row half
    const int wc = w & 1;    // col half
    const int m0 = blockIdx.x * 64;

    if (t < 192) w5s[t] = W5[t];
    if (t < 3) b5s[t] = b5[t];

    // ---- copy h2 tile (64 rows x 512 B) into swizzled LDS ----
#pragma unroll
    for (int i = 0; i < 8; ++i) {
        const int c = i * 256 + t;        // 16B chunk id, 32 per row
        const int row = c >> 5;
        const int bc = (c & 31) * 16;
        float4 v = *reinterpret_cast<const float4*>(
            reinterpret_cast<const char*>(h2B + (size_t)(m0 + row) * 256) + bc);
        *reinterpret_cast<float4*>(buf0 + ((row * 512 + bc) ^ ((row & 7) << 4))) = v;
    }

    // ---- G3: h3 = relu(h2 @ W3 + b3), out 64x128, K=256 ----
    f32x4 acc3[2][4] = {};
    const int scol = (t >> 6) * 16 + (t & 15);  // 0..63
    const int skg = (t >> 4) & 3;
    for (int kt = 0; kt < 256; kt += 32) {
        __syncthreads();
        Bs[t] = *reinterpret_cast<const float4*>(
            W3T + (size_t)scol * 256 + kt + skg * 8);
        Bs[t + 256] = *reinterpret_cast<const float4*>(
            W3T + (size_t)(scol + 64) * 256 + kt + skg * 8);
        __syncthreads();
        bf16x8 afr[2], bfr[4];
#pragma unroll
        for (int f = 0; f < 2; ++f) {
            const int row = wr * 32 + f * 16 + (l & 15);
            afr[f] = *reinterpret_cast<const bf16x8*>(
                buf0 + ((row * 512 + kt * 2 + (l >> 4) * 16) ^ ((row & 7) << 4)));
        }
#pragma unroll
        for (int g = 0; g < 4; ++g)
            bfr[g] = *reinterpret_cast<const bf16x8*>(
                &Bs[(wc * 4 + g) * 64 + (l >> 4) * 16 + (l & 15)]);
#pragma unroll
        for (int f = 0; f < 2; ++f)
#pragma unroll
            for (int g = 0; g < 4; ++g)
                acc3[f][g] = __builtin_amdgcn_mfma_f32_16x16x32_bf16(
                    afr[f], bfr[g], acc3[f][g], 0, 0, 0);
    }
    __syncthreads();
#pragma unroll
    for (int g = 0; g < 4; ++g) {
        const int col = wc * 64 + g * 16 + (l & 15);
        const float bv = b3[col];
#pragma unroll
        for (int f = 0; f < 2; ++f)
#pragma unroll
            for (int r = 0; r < 4; ++r) {
                const int row = wr * 32 + f * 16 + (l >> 4) * 4 + r;
                const float v = fmaxf(acc3[f][g][r] + bv, 0.f);
                *reinterpret_cast<unsigned short*>(
                    h3buf + ((row * 256 + col * 2) ^ ((row & 7) << 4))) =
                    (unsigned short)f2bf(v);
            }
    }

    // ---- G4: h4 = relu(h3 @ W4 + b4), out 64x64, K=128 ----
    f32x4 acc4[2][2] = {};
    for (int kt = 0; kt < 128; kt += 32) {
        __syncthreads();
        Bs[t] = *reinterpret_cast<const float4*>(
            W4T + (size_t)scol * 128 + kt + skg * 8);
        __syncthreads();
        bf16x8 afr[2], bfr[2];
#pragma unroll
        for (int f = 0; f < 2; ++f) {
            const int row = wr * 32 + f * 16 + (l & 15);
            afr[f] = *reinterpret_cast<const bf16x8*>(
                h3buf + ((row * 256 + kt * 2 + (l >> 4) * 16) ^ ((row & 7) << 4)));
        }
#pragma unroll
        for (int g = 0; g < 2; ++g)
            bfr[g] = *reinterpret_cast<const bf16x8*>(
                &Bs[(wc * 2 + g) * 64 + (l >> 4) * 16 + (l & 15)]);
#pragma unroll
        for (int f = 0; f < 2; ++f)
#pragma unroll
            for (int g = 0; g < 2; ++g)
                acc4[f][g] = __builtin_amdgcn_mfma_f32_16x16x32_bf16(
                    afr[f], bfr[g], acc4[f][g], 0, 0, 0);
    }
    __syncthreads();
    float* h4s = reinterpret_cast<float*>(buf0);  // [64][65] f32
#pragma unroll
    for (int g = 0; g < 2; ++g) {
        const int col = wc * 32 + g * 16 + (l & 15);
        const float bv = b4[col];
#pragma unroll
        for (int f = 0; f < 2; ++f)
#pragma unroll
            for (int r = 0; r < 4; ++r) {
                const int row = wr * 32 + f * 16 + (l >> 4) * 4 + r;
                h4s[row * 65 + col] = fmaxf(acc4[f][g][r] + bv, 0.f);
            }
    }
    __syncthreads();

    // ---- final: logits + softmax, one thread per row ----
    if (t < 64) {
        float a0 = b5s[0], a1 = b5s[1], a2 = b5s[2];
        const float* hr = &h4s[t * 65];
#pragma unroll
        for (int k = 0; k < 64; ++k) {
            float h = hr[k];
            a0 = fmaf(h, w5s[k * 3 + 0], a0);
            a1 = fmaf(h, w5s[k * 3 + 1], a1);
            a2 = fmaf(h, w5s[k * 3 + 2], a2);
        }
        float m  = fmaxf(a0, fmaxf(a1, a2));
        float e0 = expf(a0 - m), e1 = expf(a1 - m), e2 = expf(a2 - m);
        float inv = 1.0f / (e0 + e1 + e2);
        out[(m0 + t) * 3 + 0] = e0 * inv;
        out[(m0 + t) * 3 + 1] = e1 * inv;
        out[(m0 + t) * 3 + 2] = e2 * inv;
    }
}

// ---------------------------------------------------------------------------
// Kernel 2b: fp32 tiled GEMM (fallback path only).
// ---------------------------------------------------------------------------
template <int N, int K>
__global__ __launch_bounds__(256) void gemm_bias_relu(
    const float* __restrict__ A, const float* __restrict__ W,
    const float* __restrict__ bias, float* __restrict__ C)
{
    constexpr int BK = 16, LDT = 68;
    __shared__ float As[BK][LDT];
    __shared__ float Bs[BK][LDT];

    const int t = threadIdx.x;
    const int m0 = blockIdx.x * 64;
    const int n0 = blockIdx.y * 64;

    const int arow = t >> 2;
    const int acg  = (t & 3) * 4;
    const int brow = t >> 4;
    const int bcg  = (t & 15) * 4;

    const int tr = (t >> 4) * 4;
    const int tc = (t & 15) * 4;

    float acc[4][4] = {};

    for (int kt = 0; kt < K; kt += BK) {
        float4 av = *reinterpret_cast<const float4*>(
            &A[(size_t)(m0 + arow) * K + kt + acg]);
        float4 bv = *reinterpret_cast<const float4*>(
            &W[(size_t)(kt + brow) * N + n0 + bcg]);
        __syncthreads();
        As[acg + 0][arow] = av.x;
        As[acg + 1][arow] = av.y;
        As[acg + 2][arow] = av.z;
        As[acg + 3][arow] = av.w;
        *reinterpret_cast<float4*>(&Bs[brow][bcg]) = bv;
        __syncthreads();
#pragma unroll
        for (int kk = 0; kk < BK; ++kk) {
            float4 a4 = *reinterpret_cast<const float4*>(&As[kk][tr]);
            float4 b4 = *reinterpret_cast<const float4*>(&Bs[kk][tc]);
            float aa[4] = {a4.x, a4.y, a4.z, a4.w};
            float bb[4] = {b4.x, b4.y, b4.z, b4.w};
#pragma unroll
            for (int i = 0; i < 4; ++i)
#pragma unroll
                for (int j = 0; j < 4; ++j)
                    acc[i][j] = fmaf(aa[i], bb[j], acc[i][j]);
        }
    }

    float4 bias4 = *reinterpret_cast<const float4*>(&bias[n0 + tc]);
    float bb[4] = {bias4.x, bias4.y, bias4.z, bias4.w};
#pragma unroll
    for (int i = 0; i < 4; ++i) {
        float4 r;
        r.x = fmaxf(acc[i][0] + bb[0], 0.f);
        r.y = fmaxf(acc[i][1] + bb[1], 0.f);
        r.z = fmaxf(acc[i][2] + bb[2], 0.f);
        r.w = fmaxf(acc[i][3] + bb[3], 0.f);
        *reinterpret_cast<float4*>(&C[(size_t)(m0 + tr + i) * N + n0 + tc]) = r;
    }
}

__global__ __launch_bounds__(256) void final_softmax_kernel(
    const float* __restrict__ h4, const float* __restrict__ W5,
    const float* __restrict__ b5, float* __restrict__ out)
{
    __shared__ float w[64 * 3];
    __shared__ float bb[3];
    const int t = threadIdx.x;
    if (t < 192) w[t] = W5[t];
    if (t < 3) bb[t] = b5[t];
    __syncthreads();

    const int row = blockIdx.x * 256 + t;
    float a0 = bb[0], a1 = bb[1], a2 = bb[2];
    const float* hr = h4 + (size_t)row * 64;
#pragma unroll
    for (int k = 0; k < 64; ++k) {
        float h = hr[k];
        a0 = fmaf(h, w[k * 3 + 0], a0);
        a1 = fmaf(h, w[k * 3 + 1], a1);
        a2 = fmaf(h, w[k * 3 + 2], a2);
    }
    float m  = fmaxf(a0, fmaxf(a1, a2));
    float e0 = expf(a0 - m), e1 = expf(a1 - m), e2 = expf(a2 - m);
    float inv = 1.0f / (e0 + e1 + e2);
    out[row * 3 + 0] = e0 * inv;
    out[row * 3 + 1] = e1 * inv;
    out[row * 3 + 2] = e2 * inv;
}

// ---------------------------------------------------------------------------
// Workspace layout (fp8 path), bytes:
//   Eb8   @ 0          : 51,200,000
//   W1T   @ 51,200,000 :    524,288
//   W2T   @ 51,724,288 :    262,144
//   W3T   @ 51,986,432 :     65,536
//   W4T   @ 52,051,968 :     16,384
//   sentB @ 52,068,352 :  4,194,304
//   h1B   @ 56,262,656 :  4,194,304
//   h2B   @ 60,456,960 :  2,097,152   total 62,554,112
// ---------------------------------------------------------------------------
extern "C" void kernel_launch(void* const* d_in, const int* in_sizes, int n_in,
                              void* d_out, int out_size, void* d_ws,
                              size_t ws_size, hipStream_t stream)
{
    const int*   inputs = (const int*)d_in[0];
    const float* E  = (const float*)d_in[1];
    const float* W1 = (const float*)d_in[2];
    const float* b1 = (const float*)d_in[3];
    const float* W2 = (const float*)d_in[4];
    const float* b2 = (const float*)d_in[5];
    const float* W3 = (const float*)d_in[6];
    const float* b3 = (const float*)d_in[7];
    const float* W4 = (const float*)d_in[8];
    const float* b4 = (const float*)d_in[9];
    const float* W5 = (const float*)d_in[10];
    const float* b5 = (const float*)d_in[11];
    float* out = (float*)d_out;

    const size_t eb8Bytes = (size_t)VOCAB * EMB;  // 51,200,000
    const size_t needed = 62554112;

    if (ws_size >= needed) {
        char* p = (char*)d_ws;
        unsigned char* Eb8  = (unsigned char*)p;
        short*        W1T   = (short*)(p + eb8Bytes);
        short*        W2T   = (short*)(p + eb8Bytes + 524288);
        short*        W3T   = (short*)(p + eb8Bytes + 786432);
        short*        W4T   = (short*)(p + eb8Bytes + 851968);
        unsigned int* sentB = (unsigned int*)(p + eb8Bytes + 868352);
        short*        h1B   = (short*)(p + eb8Bytes + 868352 + 4194304);
        short*        h2B   = (short*)(p + eb8Bytes + 868352 + 2 * 4194304);

        ConvArgs ca = {E, (u32x2*)Eb8, VOCAB * EMB / 8,
                       W1, W2, W3, W4, W1T, W2T, W3T, W4T};
        convert_all<<<2472, 256, 0, stream>>>(ca);
        embed_mean_fp8<<<BATCH, 256, 0, stream>>>(inputs, Eb8, sentB);

        gemm_mfma_bias_relu<512, 512, true>
            <<<dim3(BATCH / 128, 8), 256, 0, stream>>>(
                (const short*)sentB, W1T, b1, (void*)h1B);
        gemm_mfma_bias_relu<256, 512, true>
            <<<dim3(BATCH / 128, 4), 256, 0, stream>>>(
                h1B, W2T, b2, (void*)h2B);
        mlp_tail<<<BATCH / 64, 256, 0, stream>>>(
            h2B, W3T, b3, W4T, b4, W5, b5, out);
    } else {
        float* act  = (float*)d_ws;
        float* sent = act;
        float* h1   = act + 2097152;
        float* h2   = act;
        float* h3   = act + 2097152;
        float* h4   = act;
        embed_mean_kernel<<<BATCH, 256, 0, stream>>>(inputs, E, sent);
        gemm_bias_relu<512, 512><<<dim3(BATCH / 64, 8), 256, 0, stream>>>(
            sent, W1, b1, h1);
        gemm_bias_relu<256, 512><<<dim3(BATCH / 64, 4), 256, 0, stream>>>(
            h1, W2, b2, h2);
        gemm_bias_relu<128, 256><<<dim3(BATCH / 64, 2), 256, 0, stream>>>(
            h2, W3, b3, h3);
        gemm_bias_relu<64, 128><<<dim3(BATCH / 64, 1), 256, 0, stream>>>(
            h3, W4, b4, h4);
        final_softmax_kernel<<<BATCH / 256, 256, 0, stream>>>(h4, W5, b5, out);
    }
}